// Round 4
// baseline (480.761 us; speedup 1.0000x reference)
//
#include <hip/hip_runtime.h>
#include <stdint.h>

typedef __bf16 bf16_t;
typedef __bf16 bf16x8 __attribute__((ext_vector_type(8)));
typedef float  f32x4  __attribute__((ext_vector_type(4)));

#define MFMA16(a, b, c) __builtin_amdgcn_mfma_f32_16x16x32_bf16((a), (b), (c), 0, 0, 0)

static constexpr int kG = 4, kD = 4, kH = 512;
static constexpr int kW0T = 4 * 256 * 128;            // 131072 elements
static constexpr int kWgT = 3 * 4 * 4 * 128 * 128;    // 786432 elements

// sigma16: physical acc position p (0..127) -> logical unit u, chosen so that
// lane-quarter c4 = l>>4 holds exactly logical cols {32*kt + 8*c4 + e}, i.e.
// the 16x16x32 C/D slots of one step ARE the B-operand fragments of the next:
//   p = 16*nt + 4*c4 + q  ->  u = q + 4*(nt&1) + 8*c4 + 32*(nt>>1)
// and keep[kt] = concat(acc[2kt][0:4], acc[2kt+1][0:4]) (pure register repack).
__device__ __host__ inline int sigma16(int p) {
  return (p & 3) + 4 * ((p >> 4) & 1) + 8 * ((p >> 2) & 3) + 32 * (p >> 5);
}

// ---------------------------------------------------------------------------
// Prep: f32 weights -> bf16 frag-linear for 16x16x32, columns sigma16-permuted.
//   w0t: [g][f = ktl*8+nt][ln][e]  ktl 0..7  (K=256 DIN, identity on k)
//   wgt: [g][m = l*4+d][f = ktl*8+nt][ln][e]  ktl 0..3 (K=128, u-space on k)
// A-frag layout: i = ln&15, k = 8*(ln>>4)+e.
// ---------------------------------------------------------------------------
__global__ __launch_bounds__(256) void prep_weights(
    const float* __restrict__ W0, const float* __restrict__ Wg,
    bf16_t* __restrict__ w0t, bf16_t* __restrict__ wgt)
{
  int e = blockIdx.x * 256 + threadIdx.x;
  if (e < kW0T) {
    int g  = e >> 15;
    int r  = e & 32767;
    int f  = r >> 9;             // 0..63 = ktl*8 + nt
    int ln = (r >> 3) & 63;
    int j  = r & 7;
    int ktl = f >> 3, nt = f & 7;
    int col = sigma16(nt * 16 + (ln & 15));
    int k   = ktl * 32 + ((ln >> 4) << 3) + j;
    w0t[e] = (bf16_t)W0[k * kH + g * 128 + col];
  } else if (e < kW0T + kWgT) {
    int e2 = e - kW0T;
    int g  = e2 / (12 * 16384);
    int r2 = e2 - g * (12 * 16384);
    int m  = r2 >> 14;           // l*4 + d
    int r  = r2 & 16383;
    int f  = r >> 9;             // 0..31 = ktl*8 + nt
    int ln = (r >> 3) & 63;
    int j  = r & 7;
    int ktl = f >> 3, nt = f & 7;
    int col = sigma16(nt * 16 + (ln & 15));
    int k   = ktl * 32 + ((ln >> 4) << 3) + j;
    int l   = m >> 2, d = m & 3;
    wgt[e2] = (bf16_t)Wg[((((l * kG + g) * kD + d) * 128) + k) * 128 + col];
  }
}

// ---------------------------------------------------------------------------
// Fused network, register-resident h, 16x16x32 MFMA, occupancy-tuned.
// Block = 64 rows x one group; 4 waves, wave w owns rows r0+16w..+15
// (lane row = base + (ln&15)), full n=0..127 (8 n-tiles, acc[8] f32x4).
// LDS = EXACTLY 32 KB (weight buffer only) -> 5 blocks/CU (20 waves).
// Bias is quarter-uniform -> read straight from global in the epilogue
// (L1/L2-resident, 16-lane broadcast); consuming it also retires the older
// in-flight stage() loads, making the pre-barrier vmcnt(0) nearly free.
// Per-step: MFMA -> (lgkmcnt0+barrier) -> stage(m+1) -> epilogue(+bias loads)
// -> (vmcnt0+barrier). Final store: XOR-swizzled LDS transpose + nt stores.
// ---------------------------------------------------------------------------
__global__ __launch_bounds__(256, 4) void resnext_fused(
    const float* __restrict__ x, const float* __restrict__ b0,
    const float* __restrict__ bg, const bf16_t* __restrict__ w0t,
    const bf16_t* __restrict__ wgt, float* __restrict__ out)
{
  __shared__ bf16_t sW[16384];        // 32 KB exactly: weights / f32 store tile

  const int tid = threadIdx.x;
  const int ln  = tid & 63;
  const int wv  = tid >> 6;
  const int l15 = ln & 15;
  const int c4  = ln >> 4;

  // bijective chunked XCD swizzle; logical order r-major with g fastest so the
  // 4 same-row blocks co-reside on one XCD (x fetched ~once).
  const int bid     = blockIdx.x;
  const int logical = (bid & 7) * 512 + (bid >> 3);
  const int g  = logical & 3;
  const int r0 = (logical >> 2) << 6;

  const bf16_t* wgt_g = wgt + g * (12 * 16384);
  // per-quarter bias offset within a 128-wide slice
  const int ubq = 8 * c4;

  // async stage of chain step m -> sW (8 frags/wave, 1KB each, lane*16B dest)
  auto stage = [&](int m) {
    #pragma unroll
    for (int i = 0; i < 8; ++i) {
      int frag = wv * 8 + i;
      __builtin_amdgcn_global_load_lds(
          (const __attribute__((address_space(1))) void*)(wgt_g + m * 16384 + frag * 512 + ln * 8),
          (__attribute__((address_space(3))) void*)(&sW[frag * 512]),
          16, 0, 0);
    }
  };

  stage(0);   // step-0 weights in flight under the initial GEMM

  f32x4 acc[8];
  #pragma unroll
  for (int nt = 0; nt < 8; ++nt)
    #pragma unroll
    for (int q = 0; q < 4; ++q) acc[nt][q] = 0.f;

  // ---------- initial GEMM: K=256, A (W0t) from global/L2, B from x
  {
    const bf16_t* w0g = w0t + g * 32768;
    const float* xb = x + (size_t)(r0 + wv * 16 + l15) * 256 + c4 * 8;
    #pragma unroll
    for (int ktl = 0; ktl < 8; ++ktl) {
      f32x4 xa = *(const f32x4*)(xb + ktl * 32);
      f32x4 xc = *(const f32x4*)(xb + ktl * 32 + 4);
      bf16x8 bfr;
      #pragma unroll
      for (int q = 0; q < 4; ++q) {
        bfr[q]     = (bf16_t)xa[q];
        bfr[q + 4] = (bf16_t)xc[q];
      }
      #pragma unroll
      for (int nt = 0; nt < 8; ++nt) {
        bf16x8 a = *(const bf16x8*)(w0g + (ktl * 8 + nt) * 512 + ln * 8);
        acc[nt] = MFMA16(a, bfr, acc[nt]);
      }
    }
  }
  __syncthreads();   // full drain ONCE: step-0 weights + x loads done

  bf16x8 keep[4], x0v[4], resv[4];

  // ---------- initial epilogue: relu(x@W0 + b0) -> keep/x0/resid registers
  {
    const float* b0g = b0 + g * 128 + ubq;
    #pragma unroll
    for (int nt = 0; nt < 8; ++nt) {
      f32x4 bv = *(const f32x4*)(b0g + 4 * (nt & 1) + 32 * (nt >> 1));
      #pragma unroll
      for (int q = 0; q < 4; ++q) {
        float v = fmaxf(acc[nt][q] + bv[q], 0.f);
        keep[nt >> 1][4 * (nt & 1) + q] = (bf16_t)v;
      }
    }
  }
  #pragma unroll
  for (int t = 0; t < 4; ++t) { x0v[t] = keep[t]; resv[t] = keep[t]; }

  // ---------- chain steps m = 0..11, single weight buffer, 2 barriers/step
  #pragma unroll 1
  for (int m = 0; m < 12; ++m) {
    #pragma unroll
    for (int nt = 0; nt < 8; ++nt)
      #pragma unroll
      for (int q = 0; q < 4; ++q) acc[nt][q] = 0.f;

    #pragma unroll
    for (int ktl = 0; ktl < 4; ++ktl) {
      bf16x8 bfr = keep[ktl];
      #pragma unroll
      for (int nt = 0; nt < 8; ++nt) {
        bf16x8 a = *(const bf16x8*)(sW + (ktl * 8 + nt) * 512 + ln * 8);
        acc[nt] = MFMA16(a, bfr, acc[nt]);
      }
    }

    // all waves done reading sW -> safe to overwrite with step m+1
    asm volatile("s_waitcnt lgkmcnt(0)\n\ts_barrier" ::: "memory");
    if (m < 11) stage(m + 1);

    const bool layer_end = ((m & 3) == 3);
    // bias slice for chain step m: bg[l = m>>2][g][d = m&3][*]
    const float* bgp = bg + ((size_t)(((m >> 2) * kG + g) * kD + (m & 3))) * 128 + ubq;

    if (m < 11) {
      // epilogue overlaps the staging flight; bias loads retire older stages
      #pragma unroll
      for (int nt = 0; nt < 8; ++nt) {
        f32x4 bv = *(const f32x4*)(bgp + 4 * (nt & 1) + 32 * (nt >> 1));
        #pragma unroll
        for (int q = 0; q < 4; ++q) {
          float v = fmaxf(acc[nt][q] + bv[q], 0.f);
          if (layer_end)
            v = fmaxf(v + (float)resv[nt >> 1][4 * (nt & 1) + q], 0.f);
          keep[nt >> 1][4 * (nt & 1) + q] = (bf16_t)v;
        }
      }
      if (layer_end) {
        #pragma unroll
        for (int t = 0; t < 4; ++t) resv[t] = keep[t];
      }
      // step m+1 weights landed for every wave
      asm volatile("s_waitcnt vmcnt(0)\n\ts_barrier" ::: "memory");
    } else {
      // final: bias+relu, +resid relu, +x0 relu -> f32, via LDS transpose
      float fin[8][4];
      #pragma unroll
      for (int nt = 0; nt < 8; ++nt) {
        f32x4 bv = *(const f32x4*)(bgp + 4 * (nt & 1) + 32 * (nt >> 1));
        #pragma unroll
        for (int q = 0; q < 4; ++q) {
          float v = fmaxf(acc[nt][q] + bv[q], 0.f);
          v = fmaxf(v + (float)resv[nt >> 1][4 * (nt & 1) + q], 0.f);
          v = fmaxf(v + (float)x0v[nt >> 1][4 * (nt & 1) + q], 0.f);
          fin[nt][q] = v;
        }
      }

      // 64 x 128 f32 tile (32 KB) aliases sW; reads were barriered above
      float* sT = (float*)sW;
      const int row = wv * 16 + l15;
      #pragma unroll
      for (int nt = 0; nt < 8; ++nt) {
        const int ub = 4 * (nt & 1) + 8 * c4 + 32 * (nt >> 1);
        int col_s = ub ^ ((l15 & 7) << 2);
        f32x4 v;
        #pragma unroll
        for (int q = 0; q < 4; ++q) v[q] = fin[nt][q];
        *(f32x4*)(sT + row * 128 + col_s) = v;
      }
      __syncthreads();

      #pragma unroll
      for (int it = 0; it < 8; ++it) {
        int chunk = it * 256 + tid;
        int rw = chunk >> 5, c = chunk & 31;
        int col_s = (4 * c) ^ ((rw & 7) << 2);
        f32x4 v = *(const f32x4*)(sT + rw * 128 + col_s);
        // nontemporal: bypass L2 write-allocate for the streaming output
        __builtin_nontemporal_store(
            v, (f32x4*)(out + (size_t)(r0 + rw) * kH + g * 128 + 4 * c));
      }
    }
  }
}

extern "C" void kernel_launch(void* const* d_in, const int* in_sizes, int n_in,
                              void* d_out, int out_size, void* d_ws, size_t ws_size,
                              hipStream_t stream) {
  const float* x  = (const float*)d_in[0];
  const float* W0 = (const float*)d_in[1];
  const float* b0 = (const float*)d_in[2];
  const float* Wg = (const float*)d_in[3];
  const float* bg = (const float*)d_in[4];
  float* outp = (float*)d_out;

  bf16_t* w0t = (bf16_t*)d_ws;
  bf16_t* wgt = w0t + kW0T;

  const int prep_total = kW0T + kWgT;
  prep_weights<<<(prep_total + 255) / 256, 256, 0, stream>>>(W0, Wg, w0t, wgt);

  resnext_fused<<<4096, 256, 0, stream>>>(x, b0, bg, w0t, wgt, outp);
}

// Round 5
// 473.836 us; speedup vs baseline: 1.0146x; 1.0146x over previous
//
#include <hip/hip_runtime.h>
#include <stdint.h>

typedef __bf16 bf16_t;
typedef __bf16 bf16x8 __attribute__((ext_vector_type(8)));
typedef float  f32x4  __attribute__((ext_vector_type(4)));

#define MFMA16(a, b, c) __builtin_amdgcn_mfma_f32_16x16x32_bf16((a), (b), (c), 0, 0, 0)

static constexpr int kG = 4, kD = 4, kH = 512;
static constexpr int kW0T = 4 * 256 * 128;            // 131072 elements
static constexpr int kWgT = 3 * 4 * 4 * 128 * 128;    // 786432 elements

// sigma16: physical acc position p (0..127) -> logical unit u, chosen so that
// lane-quarter c4 = l>>4 holds exactly logical cols {32*kt + 8*c4 + e}, i.e.
// the 16x16x32 C/D slots of one step ARE the B-operand fragments of the next:
//   p = 16*nt + 4*c4 + q  ->  u = q + 4*(nt&1) + 8*c4 + 32*(nt>>1)
// and keep[kt] = concat(acc[2kt][0:4], acc[2kt+1][0:4]) (pure register repack).
__device__ __host__ inline int sigma16(int p) {
  return (p & 3) + 4 * ((p >> 4) & 1) + 8 * ((p >> 2) & 3) + 32 * (p >> 5);
}

// ---------------------------------------------------------------------------
// Prep: f32 weights -> bf16 frag-linear for 16x16x32, columns sigma16-permuted.
//   w0t: [g][f = ktl*8+nt][ln][e]  ktl 0..7  (K=256 DIN, identity on k)
//   wgt: [g][m = l*4+d][f = ktl*8+nt][ln][e]  ktl 0..3 (K=128, u-space on k)
// A-frag layout: i = ln&15, k = 8*(ln>>4)+e.
// ---------------------------------------------------------------------------
__global__ __launch_bounds__(256) void prep_weights(
    const float* __restrict__ W0, const float* __restrict__ Wg,
    bf16_t* __restrict__ w0t, bf16_t* __restrict__ wgt)
{
  int e = blockIdx.x * 256 + threadIdx.x;
  if (e < kW0T) {
    int g  = e >> 15;
    int r  = e & 32767;
    int f  = r >> 9;             // 0..63 = ktl*8 + nt
    int ln = (r >> 3) & 63;
    int j  = r & 7;
    int ktl = f >> 3, nt = f & 7;
    int col = sigma16(nt * 16 + (ln & 15));
    int k   = ktl * 32 + ((ln >> 4) << 3) + j;
    w0t[e] = (bf16_t)W0[k * kH + g * 128 + col];
  } else if (e < kW0T + kWgT) {
    int e2 = e - kW0T;
    int g  = e2 / (12 * 16384);
    int r2 = e2 - g * (12 * 16384);
    int m  = r2 >> 14;           // l*4 + d
    int r  = r2 & 16383;
    int f  = r >> 9;             // 0..31 = ktl*8 + nt
    int ln = (r >> 3) & 63;
    int j  = r & 7;
    int ktl = f >> 3, nt = f & 7;
    int col = sigma16(nt * 16 + (ln & 15));
    int k   = ktl * 32 + ((ln >> 4) << 3) + j;
    int l   = m >> 2, d = m & 3;
    wgt[e2] = (bf16_t)Wg[((((l * kG + g) * kD + d) * 128) + k) * 128 + col];
  }
}

// ---------------------------------------------------------------------------
// Fused network, register-resident h, 16x16x32 MFMA (round-3 base structure).
// Block = 64 rows x one group; 4 waves, wave w owns rows r0+16w..+15,
// full n=0..127 (8 n-tiles, acc[8] f32x4). LDS 39.4 KB -> 4 blocks/CU.
//
// Dual-pipe A-operand split (this round's lever): n-tiles 0..3 come from a
// 16 KB LDS-staged half (global_load_lds DMA, compact layout); n-tiles 4..7
// are read DIRECTLY from global (L2-hot, shared by 512 blocks) into a
// 4-frag register buffer, software-pipelined one ktl ahead. Halves the DS
// read pipe (the dominant consumer at 45% of wall) and the staging drain,
// moving the other half onto the idle vector-memory/L2 path.
// Per-step: MFMA(ds+global) -> pref(m+1,ktl0) -> (lgkm0+barrier) -> stage(m+1)
// -> bias epilogue (bias from LDS) -> (vmcnt0+barrier).
// Final store via XOR-swizzled 64x128 f32 LDS transpose.
// ---------------------------------------------------------------------------
__global__ __launch_bounds__(256, 4) void resnext_fused(
    const float* __restrict__ x, const float* __restrict__ b0,
    const float* __restrict__ bg, const bf16_t* __restrict__ w0t,
    const bf16_t* __restrict__ wgt, float* __restrict__ out)
{
  __shared__ bf16_t sW[16384];        // first 16 KB: weight half; all 32 KB: f32 tile
  __shared__ float  sBias[13 * 128];  // slot 0 = b0, slots 1..12 = bg steps

  const int tid = threadIdx.x;
  const int ln  = tid & 63;
  const int wv  = tid >> 6;
  const int l15 = ln & 15;
  const int c4  = ln >> 4;

  // bijective chunked XCD swizzle; logical order r-major with g fastest so the
  // 4 same-row blocks co-reside on one XCD (x fetched ~once).
  const int bid     = blockIdx.x;
  const int logical = (bid & 7) * 512 + (bid >> 3);
  const int g  = logical & 3;
  const int r0 = (logical >> 2) << 6;

  const bf16_t* wgt_g = wgt + g * (12 * 16384);

  // stage biases (b0 slice + 12 bg slices), logical-u order
  for (int i = tid; i < 13 * 128; i += 256) {
    float v;
    if (i < 128) v = b0[g * 128 + i];
    else {
      int m = (i - 128) >> 7, u = (i - 128) & 127;
      int l = m >> 2, d = m & 3;
      v = bg[((l * kG + g) * kD + d) * 128 + u];
    }
    sBias[i] = v;
  }

  // stage LDS half of step m: n-tiles 0..3, compact frag = ktl*4+nt (16 x 1KB)
  auto stage = [&](int m) {
    #pragma unroll
    for (int i = 0; i < 4; ++i) {
      int frag = wv * 4 + i;                       // 0..15
      int gf   = (frag >> 2) * 8 + (frag & 3);     // ktl*8 + nt, nt<4
      __builtin_amdgcn_global_load_lds(
          (const __attribute__((address_space(1))) void*)(wgt_g + m * 16384 + gf * 512 + ln * 8),
          (__attribute__((address_space(3))) void*)(&sW[frag * 512]),
          16, 0, 0);
    }
  };

  // register prefetch of the global half (n-tiles 4..7) of (m, ktl)
  bf16x8 aw[4];
  auto pref = [&](int m, int ktl) {
    #pragma unroll
    for (int j = 0; j < 4; ++j)
      aw[j] = *(const bf16x8*)(wgt_g + m * 16384 + (ktl * 8 + 4 + j) * 512 + ln * 8);
  };

  stage(0);   // step-0 LDS half in flight under the initial GEMM

  f32x4 acc[8];
  #pragma unroll
  for (int nt = 0; nt < 8; ++nt)
    #pragma unroll
    for (int q = 0; q < 4; ++q) acc[nt][q] = 0.f;

  // ---------- initial GEMM: K=256, A (W0t) from global/L2, B from x
  {
    const bf16_t* w0g = w0t + g * 32768;
    const float* xb = x + (size_t)(r0 + wv * 16 + l15) * 256 + c4 * 8;
    #pragma unroll
    for (int ktl = 0; ktl < 8; ++ktl) {
      f32x4 xa = *(const f32x4*)(xb + ktl * 32);
      f32x4 xc = *(const f32x4*)(xb + ktl * 32 + 4);
      bf16x8 bfr;
      #pragma unroll
      for (int q = 0; q < 4; ++q) {
        bfr[q]     = (bf16_t)xa[q];
        bfr[q + 4] = (bf16_t)xc[q];
      }
      #pragma unroll
      for (int nt = 0; nt < 8; ++nt) {
        bf16x8 a = *(const bf16x8*)(w0g + (ktl * 8 + nt) * 512 + ln * 8);
        acc[nt] = MFMA16(a, bfr, acc[nt]);
      }
    }
  }
  pref(0, 0);        // step-0 ktl0 global half (lands under the barrier)
  __syncthreads();   // full drain ONCE: sBias + step-0 LDS half + x loads done

  bf16x8 keep[4], x0v[4], resv[4];

  // ---------- initial epilogue: relu(x@W0 + b0) -> keep/x0/resid registers
  #pragma unroll
  for (int nt = 0; nt < 8; ++nt) {
    const int ub = 4 * (nt & 1) + 8 * c4 + 32 * (nt >> 1);
    f32x4 bv = *(const f32x4*)(sBias + ub);
    #pragma unroll
    for (int q = 0; q < 4; ++q) {
      float v = fmaxf(acc[nt][q] + bv[q], 0.f);
      keep[nt >> 1][4 * (nt & 1) + q] = (bf16_t)v;
    }
  }
  #pragma unroll
  for (int t = 0; t < 4; ++t) { x0v[t] = keep[t]; resv[t] = keep[t]; }

  // ---------- chain steps m = 0..11, dual-pipe A, 2 barriers/step
  #pragma unroll 1
  for (int m = 0; m < 12; ++m) {
    #pragma unroll
    for (int nt = 0; nt < 8; ++nt)
      #pragma unroll
      for (int q = 0; q < 4; ++q) acc[nt][q] = 0.f;

    #pragma unroll
    for (int ktl = 0; ktl < 4; ++ktl) {
      bf16x8 bfr = keep[ktl];
      // LDS half: n-tiles 0..3 (compact layout)
      #pragma unroll
      for (int nt = 0; nt < 4; ++nt) {
        bf16x8 a = *(const bf16x8*)(sW + (ktl * 4 + nt) * 512 + ln * 8);
        acc[nt] = MFMA16(a, bfr, acc[nt]);
      }
      // global half: n-tiles 4..7 (prefetched into aw)
      #pragma unroll
      for (int nt = 4; nt < 8; ++nt)
        acc[nt] = MFMA16(aw[nt - 4], bfr, acc[nt]);
      // refill aw for the next ktl (WAR after MFMA reads issued)
      if (ktl < 3) pref(m, ktl + 1);
    }

    // next step's ktl0 global half: issued earliest, lands during stage+epilogue
    if (m < 11) pref(m + 1, 0);

    // all waves done reading sW -> safe to overwrite with step m+1
    asm volatile("s_waitcnt lgkmcnt(0)\n\ts_barrier" ::: "memory");
    if (m < 11) stage(m + 1);

    const bool layer_end = ((m & 3) == 3);
    const float* bptr = sBias + (m + 1) * 128;

    if (m < 11) {
      // epilogue overlaps the staging flight (bias from LDS: no vmcnt coupling)
      #pragma unroll
      for (int nt = 0; nt < 8; ++nt) {
        const int ub = 4 * (nt & 1) + 8 * c4 + 32 * (nt >> 1);
        f32x4 bv = *(const f32x4*)(bptr + ub);
        #pragma unroll
        for (int q = 0; q < 4; ++q) {
          float v = fmaxf(acc[nt][q] + bv[q], 0.f);
          if (layer_end)
            v = fmaxf(v + (float)resv[nt >> 1][4 * (nt & 1) + q], 0.f);
          keep[nt >> 1][4 * (nt & 1) + q] = (bf16_t)v;
        }
      }
      if (layer_end) {
        #pragma unroll
        for (int t = 0; t < 4; ++t) resv[t] = keep[t];
      }
      // step m+1 LDS half landed for every wave
      asm volatile("s_waitcnt vmcnt(0)\n\ts_barrier" ::: "memory");
    } else {
      // final: bias+relu, +resid relu, +x0 relu -> f32, via LDS transpose
      float fin[8][4];
      #pragma unroll
      for (int nt = 0; nt < 8; ++nt) {
        const int ub = 4 * (nt & 1) + 8 * c4 + 32 * (nt >> 1);
        f32x4 bv = *(const f32x4*)(bptr + ub);
        #pragma unroll
        for (int q = 0; q < 4; ++q) {
          float v = fmaxf(acc[nt][q] + bv[q], 0.f);
          v = fmaxf(v + (float)resv[nt >> 1][4 * (nt & 1) + q], 0.f);
          v = fmaxf(v + (float)x0v[nt >> 1][4 * (nt & 1) + q], 0.f);
          fin[nt][q] = v;
        }
      }

      // 64 x 128 f32 tile (32 KB) aliases sW; reads were barriered above
      __syncthreads();
      float* sT = (float*)sW;
      const int row = wv * 16 + l15;
      #pragma unroll
      for (int nt = 0; nt < 8; ++nt) {
        const int ub = 4 * (nt & 1) + 8 * c4 + 32 * (nt >> 1);
        int col_s = ub ^ ((l15 & 7) << 2);
        f32x4 v;
        #pragma unroll
        for (int q = 0; q < 4; ++q) v[q] = fin[nt][q];
        *(f32x4*)(sT + row * 128 + col_s) = v;
      }
      __syncthreads();

      #pragma unroll
      for (int it = 0; it < 8; ++it) {
        int chunk = it * 256 + tid;
        int rw = chunk >> 5, c = chunk & 31;
        int col_s = (4 * c) ^ ((rw & 7) << 2);
        f32x4 v = *(const f32x4*)(sT + rw * 128 + col_s);
        *(f32x4*)(out + (size_t)(r0 + rw) * kH + g * 128 + 4 * c) = v;
      }
    }
  }
}

extern "C" void kernel_launch(void* const* d_in, const int* in_sizes, int n_in,
                              void* d_out, int out_size, void* d_ws, size_t ws_size,
                              hipStream_t stream) {
  const float* x  = (const float*)d_in[0];
  const float* W0 = (const float*)d_in[1];
  const float* b0 = (const float*)d_in[2];
  const float* Wg = (const float*)d_in[3];
  const float* bg = (const float*)d_in[4];
  float* outp = (float*)d_out;

  bf16_t* w0t = (bf16_t*)d_ws;
  bf16_t* wgt = w0t + kW0T;

  const int prep_total = kW0T + kWgT;
  prep_weights<<<(prep_total + 255) / 256, 256, 0, stream>>>(W0, Wg, w0t, wgt);

  resnext_fused<<<4096, 256, 0, stream>>>(x, b0, bg, w0t, wgt, outp);
}